// Round 15
// baseline (60.743 us; speedup 1.0000x reference)
//
#include <hip/hip_runtime.h>
#include <hip/hip_fp16.h>
#include <cstdint>
#include <cstddef>

// Entropic Sinkhorn loss, MI355X / gfx950.  Round 15.
// Base = R12 (39.9us best). One change: the detector GEMM drops LDS entirely.
// fp4 inputs are 1 MiB each (L2-resident per XCD); fragment int4s are loaded
// DIRECTLY from global -- identical bytes to the staged path (the XOR swizzle
// was LDS-bank bookkeeping only). Removes all barriers / vmcnt drains / LDS
// round-trips; waves fully independent -> ~96 in-flight L2 loads per CU
// (TLP latency hiding -- the R4->R6 lesson applied to the GEMM). L2 floor
// ~7.4us (x2 read duplication). R10/R13/R14 showed intra-block scheduling
// is not the lever; the staging pipeline itself was the overhead.

#define N_DIM 8192
#define D_DIM 256
#define L2E100 144.26950408889634f  // 100 * log2(e)
#define BVAL (1.0f / 8192.0f)
#define OCAP 4                      // off-diag reg entries/thread in sinkhorn
#define NNZ_CAP (1u << 20)          // global cap; overflow -> loud NaN

typedef __attribute__((ext_vector_type(4))) float f32x4;
typedef __attribute__((ext_vector_type(8))) int i32x8;

// fp8 e5m2 (OCP) = top byte of f16.  (survivor-path + Gdiag encode semantics)
__device__ __forceinline__ unsigned char f2bf8(float f) {
  union { __half h; unsigned short u; } x;
  x.h = __float2half(fminf(f, 57344.0f));
  unsigned short r = (unsigned short)(x.u + 0x7F + ((x.u >> 8) & 1));
  return (unsigned char)(r >> 8);
}
__device__ __forceinline__ float bf8tof(unsigned char b) {
  union { unsigned short u; __half h; } x; x.u = (unsigned short)((unsigned int)b << 8);
  return __half2float(x.h);
}
__device__ __forceinline__ unsigned int pack4_bf8(float a, float b, float c, float d) {
#if __has_builtin(__builtin_amdgcn_cvt_pk_bf8_f32)
  int u = 0;
  u = __builtin_amdgcn_cvt_pk_bf8_f32(a, b, u, false);   // bytes 0,1
  u = __builtin_amdgcn_cvt_pk_bf8_f32(c, d, u, true);    // bytes 2,3
  return (unsigned int)u;
#else
  return (unsigned int)f2bf8(a) | ((unsigned int)f2bf8(b) << 8) |
         ((unsigned int)f2bf8(c) << 16) | ((unsigned int)f2bf8(d) << 24);
#endif
}
// fp4 e2m1 nibble of (a * 16) -- value grid {0,.5,1,1.5,2,3,4,6}.
__device__ __forceinline__ unsigned int fp4nib(float a) {
  float v = fabsf(a) * 16.0f;
  unsigned int s = (__float_as_uint(a) >> 31) << 3;
  unsigned int c = (v < 0.25f) ? 0u : (v < 0.75f) ? 1u : (v < 1.25f) ? 2u
                 : (v < 1.75f) ? 3u : (v < 2.5f)  ? 4u : (v < 3.5f)  ? 5u
                 : (v < 5.0f)  ? 6u : 7u;
  return s | c;
}
__device__ __forceinline__ float frcp(float x) { return __builtin_amdgcn_rcpf(x); }

// ---------------- 1. fused: fp32 -> fp4 cast + diag dot -> E_i, Thr_i, Gdiag_i ----------------
// (R12 verbatim) 512 blocks x 256 thr; thread handles one 16-value row-segment per matrix.
__global__ __launch_bounds__(256) void cast_diag_kernel(const float* __restrict__ img,
                                                        const float* __restrict__ txt,
                                                        unsigned char* __restrict__ A4,
                                                        unsigned char* __restrict__ B4,
                                                        float* __restrict__ Ecol,
                                                        float* __restrict__ Thr,
                                                        float* __restrict__ Gdiag,
                                                        unsigned int* __restrict__ cnt,
                                                        float* __restrict__ out) {
  if (blockIdx.x == 0 && threadIdx.x == 0) { cnt[0] = 0u; out[0] = 0.0f; }
  const int t = threadIdx.x, lane = t & 63, wid = t >> 6;
  const int rowg = lane >> 4, seg = lane & 15;
  const int row = blockIdx.x * 16 + wid * 4 + rowg;
  const size_t base = (size_t)row * D_DIM + seg * 16;
  float av[16], bv[16];
  #pragma unroll
  for (int h = 0; h < 4; ++h) {
    float4 a4 = *reinterpret_cast<const float4*>(img + base + h * 4);
    float4 b4 = *reinterpret_cast<const float4*>(txt + base + h * 4);
    av[4*h] = a4.x; av[4*h+1] = a4.y; av[4*h+2] = a4.z; av[4*h+3] = a4.w;
    bv[4*h] = b4.x; bv[4*h+1] = b4.y; bv[4*h+2] = b4.z; bv[4*h+3] = b4.w;
  }
  float s = 0.0f;
  #pragma unroll
  for (int e = 0; e < 16; ++e) s += av[e] * bv[e];
  unsigned int wa0 = 0, wa1 = 0, wb0 = 0, wb1 = 0;
  #pragma unroll
  for (int e = 0; e < 8; ++e) {
    wa0 |= fp4nib(av[e]) << (4 * e);
    wa1 |= fp4nib(av[8 + e]) << (4 * e);
    wb0 |= fp4nib(bv[e]) << (4 * e);
    wb1 |= fp4nib(bv[8 + e]) << (4 * e);
  }
  *reinterpret_cast<uint2*>(A4 + (size_t)row * 128 + seg * 8) = make_uint2(wa0, wa1);
  *reinterpret_cast<uint2*>(B4 + (size_t)row * 128 + seg * 8) = make_uint2(wb0, wb1);
  s += __shfl_xor(s, 1, 64); s += __shfl_xor(s, 2, 64);
  s += __shfl_xor(s, 4, 64); s += __shfl_xor(s, 8, 64);
  if (seg == 0) {
    const float E = rintf((1.0f - s) * L2E100);
    Ecol[row] = E;
    Thr[row] = (L2E100 - 19.5f - E) / L2E100;         // acc > Thr <=> x > -19.5
    Gdiag[row] = bf8tof(f2bf8(exp2f(E - (1.0f - s) * L2E100)));  // exact diag semantics
  }
}

// ---------------- 2. MX-fp4 detector GEMM, direct-from-L2 fragments ----------------
// 4096 blocks x 256 thr (4 waves 2x2; wave tile 64x64 = 4x4 frags of 16x16).
// NO LDS, NO barriers: each thread loads its fragment int4s directly from
// A4/B4 (L2-resident). Fragment (row, k-chunk lb) lives at row*128 + lb*16;
// lb = ks*4 + kh. Waves fully independent; compiler pipelines loads vs MFMA.
// XCD-bijective block swizzle (4096 % 8 == 0) keeps each XCD's working set
// in its private L2.
__global__ __launch_bounds__(256, 3) void gemm_fp4_direct_kernel(
    const unsigned char* __restrict__ A4, const unsigned char* __restrict__ B4,
    const float* __restrict__ Ecol, const float* __restrict__ Thr,
    uint2* __restrict__ entries, unsigned int* __restrict__ cnt) {
  const int bid = blockIdx.x;
  const int sid = (bid & 7) * 512 + (bid >> 3);   // bijective XCD swizzle
  const int bi = sid >> 6, bj = sid & 63;
  const int t = threadIdx.x, lane = t & 63, wid = t >> 6;
  const int wr = wid >> 1, wc = wid & 1;
  const int al = lane & 15, kh = lane >> 4;

  const unsigned char* Abase = A4 + (size_t)(bi * 128) * 128;
  const unsigned char* Bbase = B4 + (size_t)(bj * 128) * 128;

  float4 th[4];
  #pragma unroll
  for (int m = 0; m < 4; ++m)
    th[m] = *reinterpret_cast<const float4*>(Thr + bi * 128 + wr * 64 + m * 16 + kh * 4);

  f32x4 acc[4][4] = {};

  #pragma unroll
  for (int ks = 0; ks < 2; ++ks) {
    const int coff = (ks * 4 + kh) * 16;          // 16B k-chunk within the 128B row
    int4 ar[4], br[4];
    #pragma unroll
    for (int m = 0; m < 4; ++m)
      ar[m] = *reinterpret_cast<const int4*>(Abase + (wr * 64 + m * 16 + al) * 128 + coff);
    #pragma unroll
    for (int n = 0; n < 4; ++n)
      br[n] = *reinterpret_cast<const int4*>(Bbase + (wc * 64 + n * 16 + al) * 128 + coff);
    #pragma unroll
    for (int n = 0; n < 4; ++n) {
      i32x8 bvv = {br[n].x, br[n].y, br[n].z, br[n].w, 0, 0, 0, 0};
      #pragma unroll
      for (int m = 0; m < 4; ++m) {
        i32x8 avv = {ar[m].x, ar[m].y, ar[m].z, ar[m].w, 0, 0, 0, 0};
        acc[m][n] = __builtin_amdgcn_mfma_scale_f32_16x16x128_f8f6f4(
            avv, bvv, acc[m][n],
            4, 4,                 // cbsz = blgp = 4 : fp4 (e2m1) A and B
            0, 0x7B7B7B7B,        // scale A: E8M0 0x7B = 2^-4 (undoes *16)
            0, 0x7B7B7B7B);       // scale B
      }
    }
  }

  // epilogue: i = bi*128 + wr*64 + m*16 + kh*4 + q ; j = bj*128 + wc*64 + n*16 + al
  #pragma unroll
  for (int m = 0; m < 4; ++m) {
    const int ibase = bi * 128 + wr * 64 + m * 16 + kh * 4;
    #pragma unroll
    for (int n = 0; n < 4; ++n) {
      const bool hit = (acc[m][n][0] > th[m].x) | (acc[m][n][1] > th[m].y) |
                       (acc[m][n][2] > th[m].z) | (acc[m][n][3] > th[m].w);
      if (hit) {  // rare: exact fp8-byte path (R7-R14 validated)
        float4 e4 = *reinterpret_cast<const float4*>(Ecol + ibase);
        float x[4] = {fmaf(acc[m][n][0], L2E100, e4.x - L2E100),
                      fmaf(acc[m][n][1], L2E100, e4.y - L2E100),
                      fmaf(acc[m][n][2], L2E100, e4.z - L2E100),
                      fmaf(acc[m][n][3], L2E100, e4.w - L2E100)};
        unsigned int w = pack4_bf8(exp2f(fminf(x[0], 14.0f)), exp2f(fminf(x[1], 14.0f)),
                                   exp2f(fminf(x[2], 14.0f)), exp2f(fminf(x[3], 14.0f)));
        if (w != 0u) {
          const int jg = bj * 128 + wc * 64 + n * 16 + al;
          #pragma unroll
          for (int q = 0; q < 4; ++q) {
            unsigned int byte = (w >> (8 * q)) & 0xFFu;
            const int ig = ibase + q;
            if (byte && ig != jg) {
              unsigned int slot = atomicAdd(cnt, 1u);
              if (slot < NNZ_CAP)
                entries[slot] = make_uint2(((unsigned int)jg << 13) | (unsigned int)ig,
                                           __float_as_uint(bf8tof((unsigned char)byte)));
            }
          }
        }
      }
    }
  }
}

// ---------------- 3. Sinkhorn on diag+sparse (R12 verbatim) ----------------
// Fast path noff==0: diag-only Sinkhorn collapses analytically (P_ii = 1
// independent of gd) => loss = log(8191+e) - 1. General path for noff > 0.
__global__ __launch_bounds__(1024) void sinkhorn_diag_kernel(
    const uint2* __restrict__ entries, const unsigned int* __restrict__ pCnt,
    const float* __restrict__ Gdiag, float2* __restrict__ tailScr,
    float* __restrict__ out) {
  const int t = threadIdx.x;
  const int i0 = t * 8;
  __shared__ float rowB[2][8192];
  __shared__ float colB[2][8192];
  const unsigned int raw = pCnt[0];
  const int noff = (int)(raw > NNZ_CAP ? NNZ_CAP : raw);

  if (noff == 0) {  // uniform branch: closed form
    if (t == 0) out[0] = logf(8191.0f + 2.71828182845904523f) - 1.0f;
    return;
  }

  float gd[8];
  {
    float4 g0 = *reinterpret_cast<const float4*>(Gdiag + i0);
    float4 g1 = *reinterpret_cast<const float4*>(Gdiag + i0 + 4);
    gd[0] = g0.x; gd[1] = g0.y; gd[2] = g0.z; gd[3] = g0.w;
    gd[4] = g1.x; gd[5] = g1.y; gd[6] = g1.z; gd[7] = g1.w;
  }
  unsigned int erc[OCAP];
  float eg[OCAP];
  #pragma unroll
  for (int k = 0; k < OCAP; ++k) {
    const int e = t + k * 1024;
    if (e < noff) {
      uint2 en = entries[e];
      erc[k] = en.x; eg[k] = __uint_as_float(en.y);
    } else {
      erc[k] = 0u; eg[k] = 0.0f;
    }
  }
  const bool tail = noff > OCAP * 1024;

  #pragma unroll
  for (int p = 0; p < 10; ++p) {
    float* rowT = rowB[p & 1];
    float* colT = colB[p & 1];
    const float* rowS = rowB[(p + 1) & 1];
    const float* colS = colB[(p + 1) & 1];
    const float coeff = (p == 0 || (p & 1)) ? BVAL : 1.0f;
    #pragma unroll
    for (int h = 0; h < 2; ++h) {
      float4 rv, cv;
      if (p == 0) {
        rv = make_float4(gd[4 * h] * BVAL, gd[4 * h + 1] * BVAL,
                         gd[4 * h + 2] * BVAL, gd[4 * h + 3] * BVAL);
        cv = rv;
      } else {
        float4 cs = *reinterpret_cast<const float4*>(colS + i0 + 4 * h);
        float4 rs = *reinterpret_cast<const float4*>(rowS + i0 + 4 * h);
        rv = make_float4(gd[4 * h] * coeff * frcp(cs.x), gd[4 * h + 1] * coeff * frcp(cs.y),
                         gd[4 * h + 2] * coeff * frcp(cs.z), gd[4 * h + 3] * coeff * frcp(cs.w));
        cv = make_float4(gd[4 * h] * coeff * frcp(rs.x), gd[4 * h + 1] * coeff * frcp(rs.y),
                         gd[4 * h + 2] * coeff * frcp(rs.z), gd[4 * h + 3] * coeff * frcp(rs.w));
      }
      *reinterpret_cast<float4*>(rowT + i0 + 4 * h) = rv;
      *reinterpret_cast<float4*>(colT + i0 + 4 * h) = cv;
    }
    __syncthreads();
    #pragma unroll
    for (int k = 0; k < OCAP; ++k) {
      if (eg[k] != 0.0f) {
        const int r = (int)(erc[k] >> 13), c = (int)(erc[k] & 8191u);
        const float wcc = (p == 0) ? BVAL : coeff * frcp(colS[c]);
        const float wrr = (p == 0) ? BVAL : coeff * frcp(rowS[r]);
        atomicAdd(&rowT[r], eg[k] * wcc);
        atomicAdd(&colT[c], eg[k] * wrr);
      }
    }
    if (tail) {
      for (int e = OCAP * 1024 + t; e < noff; e += 1024) {
        uint2 en = entries[e];
        const int r = (int)(en.x >> 13), c = (int)(en.x & 8191u);
        const float g = __uint_as_float(en.y);
        const float wcc = (p == 0) ? BVAL : coeff * frcp(colS[c]);
        const float wrr = (p == 0) ? BVAL : coeff * frcp(rowS[r]);
        atomicAdd(&rowT[r], g * wcc);
        atomicAdd(&colT[c], g * wrr);
      }
    }
    __syncthreads();
  }

  const float* row9 = rowB[1]; const float* row8 = rowB[0];
  const float* col9 = colB[1]; const float* col8 = colB[0];

  float acc = 0.0f;
  float rE[8], cE[8];
  #pragma unroll
  for (int j = 0; j < 8; ++j) {
    const int i = i0 + j;
    const float u1 = frcp(row9[i]), v1 = BVAL * frcp(col8[i]);
    const float u2 = frcp(col9[i]), v2 = BVAL * frcp(row8[i]);
    const float p1 = u1 * gd[j] * v1, p2 = u2 * gd[j] * v2;
    acc -= p1 + p2;
    rE[j] = __expf(p1) - 1.0f;
    cE[j] = __expf(p2) - 1.0f;
  }
  float e1[OCAP], e2[OCAP];
  #pragma unroll
  for (int k = 0; k < OCAP; ++k) {
    if (eg[k] != 0.0f) {
      const int r = (int)(erc[k] >> 13), c = (int)(erc[k] & 8191u);
      e1[k] = __expf(frcp(row9[r]) * eg[k] * BVAL * frcp(col8[c])) - 1.0f;
      e2[k] = __expf(frcp(col9[c]) * eg[k] * BVAL * frcp(row8[r])) - 1.0f;
    } else { e1[k] = 0.0f; e2[k] = 0.0f; }
  }
  if (tail) {
    for (int e = OCAP * 1024 + t; e < noff; e += 1024) {
      uint2 en = entries[e];
      const int r = (int)(en.x >> 13), c = (int)(en.x & 8191u);
      const float g = __uint_as_float(en.y);
      tailScr[e - OCAP * 1024] =
          make_float2(__expf(frcp(row9[r]) * g * BVAL * frcp(col8[c])) - 1.0f,
                      __expf(frcp(col9[c]) * g * BVAL * frcp(row8[r])) - 1.0f);
    }
  }
  __syncthreads();

  float* rowE = rowB[0]; float* colE = colB[0];
  #pragma unroll
  for (int h = 0; h < 2; ++h) {
    *reinterpret_cast<float4*>(rowE + i0 + 4 * h) =
        make_float4(rE[4 * h], rE[4 * h + 1], rE[4 * h + 2], rE[4 * h + 3]);
    *reinterpret_cast<float4*>(colE + i0 + 4 * h) =
        make_float4(cE[4 * h], cE[4 * h + 1], cE[4 * h + 2], cE[4 * h + 3]);
  }
  __syncthreads();
  #pragma unroll
  for (int k = 0; k < OCAP; ++k) {
    if (eg[k] != 0.0f) {
      atomicAdd(&rowE[erc[k] >> 13], e1[k]);
      atomicAdd(&colE[erc[k] & 8191u], e2[k]);
    }
  }
  if (tail) {
    for (int e = OCAP * 1024 + t; e < noff; e += 1024) {
      unsigned int rc = entries[e].x;
      float2 ee = tailScr[e - OCAP * 1024];
      atomicAdd(&rowE[rc >> 13], ee.x);
      atomicAdd(&colE[rc & 8191u], ee.y);
    }
  }
  __syncthreads();

  #pragma unroll
  for (int j = 0; j < 8; ++j)
    acc += logf(8192.0f + rowE[i0 + j]) + logf(8192.0f + colE[i0 + j]);
  #pragma unroll
  for (int o = 32; o > 0; o >>= 1) acc += __shfl_down(acc, o, 64);
  __syncthreads();
  if ((t & 63) == 0) colB[1][t >> 6] = acc;
  __syncthreads();
  if (t == 0) {
    float s = 0.0f;
    #pragma unroll
    for (int w = 0; w < 16; ++w) s += colB[1][w];
    s *= 0.5f / 8192.0f;
    if (raw > NNZ_CAP) s = __int_as_float(0x7FC00000);  // fail loudly
    out[0] = s;
  }
}

// ---------------- launch ----------------
extern "C" void kernel_launch(void* const* d_in, const int* in_sizes, int n_in,
                              void* d_out, int out_size, void* d_ws, size_t ws_size,
                              hipStream_t stream) {
  const float* img = (const float*)d_in[0];
  const float* txt = (const float*)d_in[1];
  float* out = (float*)d_out;

  char* ws = (char*)d_ws;
  size_t off = 0;
  auto alloc = [&](size_t bytes) -> void* {
    void* p = ws + off;
    off += (bytes + 255) & ~(size_t)255;
    return p;
  };
  unsigned char* A4 = (unsigned char*)alloc((size_t)N_DIM * 128);  // 1 MiB fp4
  unsigned char* B4 = (unsigned char*)alloc((size_t)N_DIM * 128);  // 1 MiB fp4
  uint2* entries    = (uint2*)alloc((size_t)NNZ_CAP * 8);          // 8 MiB
  float2* tailScr   = (float2*)alloc((size_t)NNZ_CAP * 8);         // 8 MiB
  unsigned int* cnt = (unsigned int*)alloc(256);
  float* Ecol  = (float*)alloc(N_DIM * 4);
  float* Thr   = (float*)alloc(N_DIM * 4);
  float* Gdiag = (float*)alloc(N_DIM * 4);

  if (off > ws_size) {
    hipMemsetAsync(d_out, 0xFF, sizeof(float) * (out_size > 0 ? out_size : 1), stream);
    return;
  }

  cast_diag_kernel<<<512, 256, 0, stream>>>(img, txt, A4, B4, Ecol, Thr, Gdiag, cnt, out);
  gemm_fp4_direct_kernel<<<4096, 256, 0, stream>>>(A4, B4, Ecol, Thr, entries, cnt);
  sinkhorn_diag_kernel<<<1, 1024, 0, stream>>>(entries, cnt, Gdiag, tailScr, out);
}

// Round 16
// 39.758 us; speedup vs baseline: 1.5278x; 1.5278x over previous
//
#include <hip/hip_runtime.h>
#include <hip/hip_fp16.h>
#include <cstdint>
#include <cstddef>

// Entropic Sinkhorn loss, MI355X / gfx950.  Round 16 = R12 revert (session best,
// 39.9us). R13 (K-half layout split) +2.2, R14 (two-tile pipeline) +0.8,
// R15 (LDS-free direct-L2 fragments) +20.8, R10 (persistent) +19 all lost to
// this structure. Pipeline:
//   1. cast_diag: fp32 -> fp4 e2m1 (fixed scale 2^-4, stored *16) + exact
//      fp32 diag dot -> E_i, Thr_i, Gdiag_i (13-sigma detector margin).
//   2. detector GEMM: MX-scaled fp4 MFMA 16x16x128 (scale bytes 0x7B = 2^-4).
//      128^2 tile, 256 thr, 4 waves 2x2, wave tile 64x64, LDS 32 KB full-K ->
//      4 blocks/CU. Full-row 8-block XOR swizzle (pre-swizzled global source,
//      rule #21; 2-way = free). Single vmcnt(0); overlap via 4-deep residency.
//   3. sinkhorn: noff==0 -> closed form; general LDS path for noff>0.

#define N_DIM 8192
#define D_DIM 256
#define L2E100 144.26950408889634f  // 100 * log2(e)
#define BVAL (1.0f / 8192.0f)
#define OCAP 4                      // off-diag reg entries/thread in sinkhorn
#define NNZ_CAP (1u << 20)          // global cap; overflow -> loud NaN

typedef __attribute__((ext_vector_type(4))) float f32x4;
typedef __attribute__((ext_vector_type(8))) int i32x8;

// fp8 e5m2 (OCP) = top byte of f16.  (survivor-path + Gdiag encode semantics)
__device__ __forceinline__ unsigned char f2bf8(float f) {
  union { __half h; unsigned short u; } x;
  x.h = __float2half(fminf(f, 57344.0f));
  unsigned short r = (unsigned short)(x.u + 0x7F + ((x.u >> 8) & 1));
  return (unsigned char)(r >> 8);
}
__device__ __forceinline__ float bf8tof(unsigned char b) {
  union { unsigned short u; __half h; } x; x.u = (unsigned short)((unsigned int)b << 8);
  return __half2float(x.h);
}
__device__ __forceinline__ unsigned int pack4_bf8(float a, float b, float c, float d) {
#if __has_builtin(__builtin_amdgcn_cvt_pk_bf8_f32)
  int u = 0;
  u = __builtin_amdgcn_cvt_pk_bf8_f32(a, b, u, false);   // bytes 0,1
  u = __builtin_amdgcn_cvt_pk_bf8_f32(c, d, u, true);    // bytes 2,3
  return (unsigned int)u;
#else
  return (unsigned int)f2bf8(a) | ((unsigned int)f2bf8(b) << 8) |
         ((unsigned int)f2bf8(c) << 16) | ((unsigned int)f2bf8(d) << 24);
#endif
}
// fp4 e2m1 nibble of (a * 16) -- value grid {0,.5,1,1.5,2,3,4,6}.
__device__ __forceinline__ unsigned int fp4nib(float a) {
  float v = fabsf(a) * 16.0f;
  unsigned int s = (__float_as_uint(a) >> 31) << 3;
  unsigned int c = (v < 0.25f) ? 0u : (v < 0.75f) ? 1u : (v < 1.25f) ? 2u
                 : (v < 1.75f) ? 3u : (v < 2.5f)  ? 4u : (v < 3.5f)  ? 5u
                 : (v < 5.0f)  ? 6u : 7u;
  return s | c;
}
__device__ __forceinline__ float frcp(float x) { return __builtin_amdgcn_rcpf(x); }

#define GLD_LDS16(g, l)                                                          \
  __builtin_amdgcn_global_load_lds(                                              \
      (const __attribute__((address_space(1))) unsigned int*)(g),                \
      (__attribute__((address_space(3))) unsigned int*)(l), 16, 0, 0)

// ---------------- 1. fused: fp32 -> fp4 cast + diag dot -> E_i, Thr_i, Gdiag_i ----------------
// 512 blocks x 256 thr; thread handles one row-segment of 16 values per matrix.
__global__ __launch_bounds__(256) void cast_diag_kernel(const float* __restrict__ img,
                                                        const float* __restrict__ txt,
                                                        unsigned char* __restrict__ A4,
                                                        unsigned char* __restrict__ B4,
                                                        float* __restrict__ Ecol,
                                                        float* __restrict__ Thr,
                                                        float* __restrict__ Gdiag,
                                                        unsigned int* __restrict__ cnt,
                                                        float* __restrict__ out) {
  if (blockIdx.x == 0 && threadIdx.x == 0) { cnt[0] = 0u; out[0] = 0.0f; }
  const int t = threadIdx.x, lane = t & 63, wid = t >> 6;
  const int rowg = lane >> 4, seg = lane & 15;
  const int row = blockIdx.x * 16 + wid * 4 + rowg;
  const size_t base = (size_t)row * D_DIM + seg * 16;
  float av[16], bv[16];
  #pragma unroll
  for (int h = 0; h < 4; ++h) {
    float4 a4 = *reinterpret_cast<const float4*>(img + base + h * 4);
    float4 b4 = *reinterpret_cast<const float4*>(txt + base + h * 4);
    av[4*h] = a4.x; av[4*h+1] = a4.y; av[4*h+2] = a4.z; av[4*h+3] = a4.w;
    bv[4*h] = b4.x; bv[4*h+1] = b4.y; bv[4*h+2] = b4.z; bv[4*h+3] = b4.w;
  }
  float s = 0.0f;
  #pragma unroll
  for (int e = 0; e < 16; ++e) s += av[e] * bv[e];
  // pack 16 fp4 nibbles -> 8 bytes per matrix (element 2k low nibble, 2k+1 high)
  unsigned int wa0 = 0, wa1 = 0, wb0 = 0, wb1 = 0;
  #pragma unroll
  for (int e = 0; e < 8; ++e) {
    wa0 |= fp4nib(av[e]) << (4 * e);
    wa1 |= fp4nib(av[8 + e]) << (4 * e);
    wb0 |= fp4nib(bv[e]) << (4 * e);
    wb1 |= fp4nib(bv[8 + e]) << (4 * e);
  }
  *reinterpret_cast<uint2*>(A4 + (size_t)row * 128 + seg * 8) = make_uint2(wa0, wa1);
  *reinterpret_cast<uint2*>(B4 + (size_t)row * 128 + seg * 8) = make_uint2(wb0, wb1);
  s += __shfl_xor(s, 1, 64); s += __shfl_xor(s, 2, 64);
  s += __shfl_xor(s, 4, 64); s += __shfl_xor(s, 8, 64);
  if (seg == 0) {
    const float E = rintf((1.0f - s) * L2E100);
    Ecol[row] = E;
    Thr[row] = (L2E100 - 19.5f - E) / L2E100;         // acc > Thr <=> x > -19.5
    Gdiag[row] = bf8tof(f2bf8(exp2f(E - (1.0f - s) * L2E100)));  // exact diag semantics
  }
}

// ---------------- 2. MX-fp4 detector GEMM ----------------
// 4096 blocks x 256 thr (4 waves 2x2; wave tile 64x64 = 4x4 frags of 16x16).
// LDS 32 KB: A[128][128B] @0, B @16K (full K=256 as fp4). 8 global_load_lds
// up front -> vmcnt(0) -> one barrier -> 2 ksteps x 16 MFMA. 4 blocks/CU.
// Swizzle: phys 16B block p of row r holds logical block p^(r&7); staging
// pre-swizzles the per-lane GLOBAL source (linear LDS dest, rule #21).
// XCD-bijective block swizzle (4096 % 8 == 0).
__global__ __launch_bounds__(256, 4) void gemm_fp4_sparse_kernel(
    const unsigned char* __restrict__ A4, const unsigned char* __restrict__ B4,
    const float* __restrict__ Ecol, const float* __restrict__ Thr,
    uint2* __restrict__ entries, unsigned int* __restrict__ cnt) {
  __shared__ __align__(16) char smem[32768];
  const int bid = blockIdx.x;
  const int sid = (bid & 7) * 512 + (bid >> 3);   // bijective XCD swizzle
  const int bi = sid >> 6, bj = sid & 63;
  const int t = threadIdx.x, lane = t & 63, wid = t >> 6;
  const int wr = wid >> 1, wc = wid & 1;
  const int al = lane & 15, kh = lane >> 4;

  // staging: inst i covers rows i*32 + (t>>3), phys 16B block t&7
  const int srow = t >> 3, sp = t & 7;
  const int sx = (sp ^ (srow & 7)) << 4;          // pre-swizzled source block
  const unsigned char* Ab = A4 + (size_t)(bi * 128) * 128;
  const unsigned char* Bb = B4 + (size_t)(bj * 128) * 128;
  #pragma unroll
  for (int i = 0; i < 4; ++i)
    GLD_LDS16(Ab + (size_t)(i * 32 + srow) * 128 + sx, smem + i * 4096 + t * 16);
  #pragma unroll
  for (int i = 0; i < 4; ++i)
    GLD_LDS16(Bb + (size_t)(i * 32 + srow) * 128 + sx, smem + 16384 + i * 4096 + t * 16);

  // prefetch thresholds (overlaps stage flight)
  float4 th[4];
  #pragma unroll
  for (int m = 0; m < 4; ++m)
    th[m] = *reinterpret_cast<const float4*>(Thr + bi * 128 + wr * 64 + m * 16 + kh * 4);

  f32x4 acc[4][4] = {};

  asm volatile("s_waitcnt vmcnt(0)" ::: "memory");
  __builtin_amdgcn_sched_barrier(0);
  __builtin_amdgcn_s_barrier();
  __builtin_amdgcn_sched_barrier(0);

  #pragma unroll
  for (int ks = 0; ks < 2; ++ks) {
    const int lb = ks * 4 + kh;                   // logical 16B block (k-chunk)
    int4 ar[4];
    #pragma unroll
    for (int m = 0; m < 4; ++m) {
      const int row = wr * 64 + m * 16 + al;
      ar[m] = *reinterpret_cast<const int4*>(smem + row * 128 + ((lb ^ (row & 7)) << 4));
    }
    #pragma unroll
    for (int n = 0; n < 4; ++n) {
      const int rowb = wc * 64 + n * 16 + al;
      int4 br = *reinterpret_cast<const int4*>(smem + 16384 + rowb * 128 +
                                               ((lb ^ (rowb & 7)) << 4));
      i32x8 bvv = {br.x, br.y, br.z, br.w, 0, 0, 0, 0};
      #pragma unroll
      for (int m = 0; m < 4; ++m) {
        i32x8 avv = {ar[m].x, ar[m].y, ar[m].z, ar[m].w, 0, 0, 0, 0};
        acc[m][n] = __builtin_amdgcn_mfma_scale_f32_16x16x128_f8f6f4(
            avv, bvv, acc[m][n],
            4, 4,                 // cbsz = blgp = 4 : fp4 (e2m1) A and B
            0, 0x7B7B7B7B,        // scale A: E8M0 0x7B = 2^-4 (undoes *16)
            0, 0x7B7B7B7B);       // scale B
      }
    }
  }

  // epilogue: i = bi*128 + wr*64 + m*16 + kh*4 + q ; j = bj*128 + wc*64 + n*16 + al
  #pragma unroll
  for (int m = 0; m < 4; ++m) {
    const int ibase = bi * 128 + wr * 64 + m * 16 + kh * 4;
    #pragma unroll
    for (int n = 0; n < 4; ++n) {
      const bool hit = (acc[m][n][0] > th[m].x) | (acc[m][n][1] > th[m].y) |
                       (acc[m][n][2] > th[m].z) | (acc[m][n][3] > th[m].w);
      if (hit) {  // rare: exact fp8-byte path (R7-R15 validated)
        float4 e4 = *reinterpret_cast<const float4*>(Ecol + ibase);
        float x[4] = {fmaf(acc[m][n][0], L2E100, e4.x - L2E100),
                      fmaf(acc[m][n][1], L2E100, e4.y - L2E100),
                      fmaf(acc[m][n][2], L2E100, e4.z - L2E100),
                      fmaf(acc[m][n][3], L2E100, e4.w - L2E100)};
        unsigned int w = pack4_bf8(exp2f(fminf(x[0], 14.0f)), exp2f(fminf(x[1], 14.0f)),
                                   exp2f(fminf(x[2], 14.0f)), exp2f(fminf(x[3], 14.0f)));
        if (w != 0u) {
          const int jg = bj * 128 + wc * 64 + n * 16 + al;
          #pragma unroll
          for (int q = 0; q < 4; ++q) {
            unsigned int byte = (w >> (8 * q)) & 0xFFu;
            const int ig = ibase + q;
            if (byte && ig != jg) {
              unsigned int slot = atomicAdd(cnt, 1u);
              if (slot < NNZ_CAP)
                entries[slot] = make_uint2(((unsigned int)jg << 13) | (unsigned int)ig,
                                           __float_as_uint(bf8tof((unsigned char)byte)));
            }
          }
        }
      }
    }
  }
}

// ---------------- 3. Sinkhorn on diag+sparse ----------------
// Fast path noff==0: diag-only Sinkhorn collapses analytically (P_ii = 1
// independent of gd) => loss = log(8191+e) - 1. General path (validated
// R6-R8) for noff > 0.
__global__ __launch_bounds__(1024) void sinkhorn_diag_kernel(
    const uint2* __restrict__ entries, const unsigned int* __restrict__ pCnt,
    const float* __restrict__ Gdiag, float2* __restrict__ tailScr,
    float* __restrict__ out) {
  const int t = threadIdx.x;
  const int i0 = t * 8;
  __shared__ float rowB[2][8192];
  __shared__ float colB[2][8192];
  const unsigned int raw = pCnt[0];
  const int noff = (int)(raw > NNZ_CAP ? NNZ_CAP : raw);

  if (noff == 0) {  // uniform branch: closed form
    if (t == 0) out[0] = logf(8191.0f + 2.71828182845904523f) - 1.0f;
    return;
  }

  float gd[8];
  {
    float4 g0 = *reinterpret_cast<const float4*>(Gdiag + i0);
    float4 g1 = *reinterpret_cast<const float4*>(Gdiag + i0 + 4);
    gd[0] = g0.x; gd[1] = g0.y; gd[2] = g0.z; gd[3] = g0.w;
    gd[4] = g1.x; gd[5] = g1.y; gd[6] = g1.z; gd[7] = g1.w;
  }
  unsigned int erc[OCAP];
  float eg[OCAP];
  #pragma unroll
  for (int k = 0; k < OCAP; ++k) {
    const int e = t + k * 1024;
    if (e < noff) {
      uint2 en = entries[e];
      erc[k] = en.x; eg[k] = __uint_as_float(en.y);
    } else {
      erc[k] = 0u; eg[k] = 0.0f;
    }
  }
  const bool tail = noff > OCAP * 1024;

  #pragma unroll
  for (int p = 0; p < 10; ++p) {
    float* rowT = rowB[p & 1];
    float* colT = colB[p & 1];
    const float* rowS = rowB[(p + 1) & 1];
    const float* colS = colB[(p + 1) & 1];
    const float coeff = (p == 0 || (p & 1)) ? BVAL : 1.0f;
    #pragma unroll
    for (int h = 0; h < 2; ++h) {
      float4 rv, cv;
      if (p == 0) {
        rv = make_float4(gd[4 * h] * BVAL, gd[4 * h + 1] * BVAL,
                         gd[4 * h + 2] * BVAL, gd[4 * h + 3] * BVAL);
        cv = rv;
      } else {
        float4 cs = *reinterpret_cast<const float4*>(colS + i0 + 4 * h);
        float4 rs = *reinterpret_cast<const float4*>(rowS + i0 + 4 * h);
        rv = make_float4(gd[4 * h] * coeff * frcp(cs.x), gd[4 * h + 1] * coeff * frcp(cs.y),
                         gd[4 * h + 2] * coeff * frcp(cs.z), gd[4 * h + 3] * coeff * frcp(cs.w));
        cv = make_float4(gd[4 * h] * coeff * frcp(rs.x), gd[4 * h + 1] * coeff * frcp(rs.y),
                         gd[4 * h + 2] * coeff * frcp(rs.z), gd[4 * h + 3] * coeff * frcp(rs.w));
      }
      *reinterpret_cast<float4*>(rowT + i0 + 4 * h) = rv;
      *reinterpret_cast<float4*>(colT + i0 + 4 * h) = cv;
    }
    __syncthreads();
    #pragma unroll
    for (int k = 0; k < OCAP; ++k) {
      if (eg[k] != 0.0f) {
        const int r = (int)(erc[k] >> 13), c = (int)(erc[k] & 8191u);
        const float wcc = (p == 0) ? BVAL : coeff * frcp(colS[c]);
        const float wrr = (p == 0) ? BVAL : coeff * frcp(rowS[r]);
        atomicAdd(&rowT[r], eg[k] * wcc);
        atomicAdd(&colT[c], eg[k] * wrr);
      }
    }
    if (tail) {
      for (int e = OCAP * 1024 + t; e < noff; e += 1024) {
        uint2 en = entries[e];
        const int r = (int)(en.x >> 13), c = (int)(en.x & 8191u);
        const float g = __uint_as_float(en.y);
        const float wcc = (p == 0) ? BVAL : coeff * frcp(colS[c]);
        const float wrr = (p == 0) ? BVAL : coeff * frcp(rowS[r]);
        atomicAdd(&rowT[r], g * wcc);
        atomicAdd(&colT[c], g * wrr);
      }
    }
    __syncthreads();
  }

  const float* row9 = rowB[1]; const float* row8 = rowB[0];
  const float* col9 = colB[1]; const float* col8 = colB[0];

  float acc = 0.0f;
  float rE[8], cE[8];
  #pragma unroll
  for (int j = 0; j < 8; ++j) {
    const int i = i0 + j;
    const float u1 = frcp(row9[i]), v1 = BVAL * frcp(col8[i]);
    const float u2 = frcp(col9[i]), v2 = BVAL * frcp(row8[i]);
    const float p1 = u1 * gd[j] * v1, p2 = u2 * gd[j] * v2;
    acc -= p1 + p2;
    rE[j] = __expf(p1) - 1.0f;
    cE[j] = __expf(p2) - 1.0f;
  }
  float e1[OCAP], e2[OCAP];
  #pragma unroll
  for (int k = 0; k < OCAP; ++k) {
    if (eg[k] != 0.0f) {
      const int r = (int)(erc[k] >> 13), c = (int)(erc[k] & 8191u);
      e1[k] = __expf(frcp(row9[r]) * eg[k] * BVAL * frcp(col8[c])) - 1.0f;
      e2[k] = __expf(frcp(col9[c]) * eg[k] * BVAL * frcp(row8[r])) - 1.0f;
    } else { e1[k] = 0.0f; e2[k] = 0.0f; }
  }
  if (tail) {
    for (int e = OCAP * 1024 + t; e < noff; e += 1024) {
      uint2 en = entries[e];
      const int r = (int)(en.x >> 13), c = (int)(en.x & 8191u);
      const float g = __uint_as_float(en.y);
      tailScr[e - OCAP * 1024] =
          make_float2(__expf(frcp(row9[r]) * g * BVAL * frcp(col8[c])) - 1.0f,
                      __expf(frcp(col9[c]) * g * BVAL * frcp(row8[r])) - 1.0f);
    }
  }
  __syncthreads();

  float* rowE = rowB[0]; float* colE = colB[0];
  #pragma unroll
  for (int h = 0; h < 2; ++h) {
    *reinterpret_cast<float4*>(rowE + i0 + 4 * h) =
        make_float4(rE[4 * h], rE[4 * h + 1], rE[4 * h + 2], rE[4 * h + 3]);
    *reinterpret_cast<float4*>(colE + i0 + 4 * h) =
        make_float4(cE[4 * h], cE[4 * h + 1], cE[4 * h + 2], cE[4 * h + 3]);
  }
  __syncthreads();
  #pragma unroll
  for (int k = 0; k < OCAP; ++k) {
    if (eg[k] != 0.0f) {
      atomicAdd(&rowE[erc[k] >> 13], e1[k]);
      atomicAdd(&colE[erc[k] & 8191u], e2[k]);
    }
  }
  if (tail) {
    for (int e = OCAP * 1024 + t; e < noff; e += 1024) {
      unsigned int rc = entries[e].x;
      float2 ee = tailScr[e - OCAP * 1024];
      atomicAdd(&rowE[rc >> 13], ee.x);
      atomicAdd(&colE[rc & 8191u], ee.y);
    }
  }
  __syncthreads();

  #pragma unroll
  for (int j = 0; j < 8; ++j)
    acc += logf(8192.0f + rowE[i0 + j]) + logf(8192.0f + colE[i0 + j]);
  #pragma unroll
  for (int o = 32; o > 0; o >>= 1) acc += __shfl_down(acc, o, 64);
  __syncthreads();
  if ((t & 63) == 0) colB[1][t >> 6] = acc;
  __syncthreads();
  if (t == 0) {
    float s = 0.0f;
    #pragma unroll
    for (int w = 0; w < 16; ++w) s += colB[1][w];
    s *= 0.5f / 8192.0f;
    if (raw > NNZ_CAP) s = __int_as_float(0x7FC00000);  // fail loudly
    out[0] = s;
  }
}

// ---------------- launch ----------------
extern "C" void kernel_launch(void* const* d_in, const int* in_sizes, int n_in,
                              void* d_out, int out_size, void* d_ws, size_t ws_size,
                              hipStream_t stream) {
  const float* img = (const float*)d_in[0];
  const float* txt = (const float*)d_in[1];
  float* out = (float*)d_out;

  char* ws = (char*)d_ws;
  size_t off = 0;
  auto alloc = [&](size_t bytes) -> void* {
    void* p = ws + off;
    off += (bytes + 255) & ~(size_t)255;
    return p;
  };
  unsigned char* A4 = (unsigned char*)alloc((size_t)N_DIM * 128);  // 1 MiB fp4
  unsigned char* B4 = (unsigned char*)alloc((size_t)N_DIM * 128);  // 1 MiB fp4
  uint2* entries    = (uint2*)alloc((size_t)NNZ_CAP * 8);          // 8 MiB
  float2* tailScr   = (float2*)alloc((size_t)NNZ_CAP * 8);         // 8 MiB
  unsigned int* cnt = (unsigned int*)alloc(256);
  float* Ecol  = (float*)alloc(N_DIM * 4);
  float* Thr   = (float*)alloc(N_DIM * 4);
  float* Gdiag = (float*)alloc(N_DIM * 4);

  if (off > ws_size) {
    hipMemsetAsync(d_out, 0xFF, sizeof(float) * (out_size > 0 ? out_size : 1), stream);
    return;
  }

  cast_diag_kernel<<<512, 256, 0, stream>>>(img, txt, A4, B4, Ecol, Thr, Gdiag, cnt, out);
  gemm_fp4_sparse_kernel<<<4096, 256, 0, stream>>>(A4, B4, Ecol, Thr, entries, cnt);
  sinkhorn_diag_kernel<<<1, 1024, 0, stream>>>(entries, cnt, Gdiag, tailScr, out);
}